// Round 2
// baseline (11903.481 us; speedup 1.0000x reference)
//
#include <hip/hip_runtime.h>

#define B_ 256
#define S_ 256
#define D_ 64
#define H_ 1024
#define G4 4096
#define TOUT 32

typedef unsigned short u16;
typedef __attribute__((ext_vector_type(8))) short short8;
typedef __attribute__((ext_vector_type(4))) float float4v;

__device__ __forceinline__ float bf2f(u16 b) {
  return __uint_as_float(((unsigned int)b) << 16);
}
__device__ __forceinline__ u16 f2bf(float f) {
  unsigned int u = __float_as_uint(f);
  unsigned int r = (u + 0x7fffu + ((u >> 16) & 1u)) >> 16;
  return (u16)r;
}
__device__ __forceinline__ unsigned pack2(float a, float b) {
  return (unsigned)f2bf(a) | ((unsigned)f2bf(b) << 16);
}
__device__ __forceinline__ float sigm(float x) {
  return 1.f / (1.f + __expf(-x));
}
__device__ __forceinline__ float tanh_(float x) {
  float xc = fminf(fmaxf(x, -15.f), 15.f);
  float e = __expf(2.f * xc);
  return (e - 1.f) / (e + 1.f);
}

// flat fp32 -> bf16 convert
__global__ __launch_bounds__(256) void cvt_kernel(const float* __restrict__ src,
                                                  u16* __restrict__ dst, int n) {
  for (int i = blockIdx.x * blockDim.x + threadIdx.x; i < n;
       i += gridDim.x * blockDim.x)
    dst[i] = f2bf(src[i]);
}

__global__ __launch_bounds__(256) void zero_kernel(uint4* __restrict__ p, int n16) {
  for (int i = blockIdx.x * blockDim.x + threadIdx.x; i < n16;
       i += gridDim.x * blockDim.x)
    p[i] = make_uint4(0u, 0u, 0u, 0u);
}

// One LSTM layer step: gates = [A0|A1] @ [W0|W1]^T + bias (+ inp*wcol), fused cell.
// Grid (64,4): blockIdx.x = 64 gate-cols (interleaved order p=4*J+g via row remap),
// blockIdx.y = 64 batches. A is bf16. W is bf16 (WF32=false, ws copies) or fp32
// originals (WF32=true fallback) in ORIGINAL torch layout [4H][K], gate-blocked rows.
template <bool WF32>
__global__ __launch_bounds__(256) void lstm_step_kernel(
    const u16* __restrict__ A0, int lda0,
    const u16* __restrict__ A1, int lda1, int klen0,
    const void* __restrict__ W0v, int ldw0,
    const void* __restrict__ W1v, int ldw1, int Ktot,
    const float* __restrict__ biasO,   // fp32 [4096] original gate-blocked
    const float* __restrict__ wcolO,   // fp32 [4096] dec input col, or null
    const float* __restrict__ inp,     // fp32 [B] scalar input, or null
    float* __restrict__ c_state,
    u16* __restrict__ h_out)
{
  __shared__ u16 As[64][72];   // +8 pad: only free 2-way conflicts (m136)
  __shared__ u16 Bs[64][72];
  __shared__ float Gs[64][68];

  const int tid = threadIdx.x;
  const int m0 = blockIdx.y * 64;
  const int n0 = blockIdx.x * 64;
  const int ub = n0 >> 2;        // first hidden unit of this block
  const int r = tid >> 2;        // staging row 0..63
  const int q = tid & 3;         // staging 16-col group
  const int lane = tid & 63;
  const int wv = tid >> 6;
  const int wm = (wv >> 1) * 32;
  const int wn = (wv & 1) * 32;
  const int l16 = lane & 15;
  const int quad = lane >> 4;

  // per-thread source row bases
  const u16* aw0 = A0 + (size_t)(m0 + r) * lda0;
  const u16* aw1 = A1 + (size_t)(m0 + r) * lda1;
  const int orow = (r & 3) * H_ + ub + (r >> 2);  // gate-col n0+r -> original row
  const u16* bw0_h = (const u16*)W0v + (size_t)orow * ldw0;
  const u16* bw1_h = (const u16*)W1v + (size_t)orow * ldw1;
  const float* bw0_f = (const float*)W0v + (size_t)orow * ldw0;
  const float* bw1_f = (const float*)W1v + (size_t)orow * ldw1;

  float4v acc00 = {}, acc01 = {}, acc10 = {}, acc11 = {};

  const int nch = Ktot >> 6;
  for (int kc = 0; kc < nch; ++kc) {
    const int kg = kc * 64 + q * 16;
    const bool first = kg < klen0;
    const u16* pa = first ? (aw0 + kg) : (aw1 + (kg - klen0));
    const uint4 av0 = *(const uint4*)pa;
    const uint4 av1 = *(const uint4*)(pa + 8);
    uint4 bv0, bv1;
    if constexpr (WF32) {
      const float* pb = first ? (bw0_f + kg) : (bw1_f + (kg - klen0));
      const float4 x0 = *(const float4*)pb;
      const float4 x1 = *(const float4*)(pb + 4);
      const float4 x2 = *(const float4*)(pb + 8);
      const float4 x3 = *(const float4*)(pb + 12);
      bv0 = make_uint4(pack2(x0.x, x0.y), pack2(x0.z, x0.w),
                       pack2(x1.x, x1.y), pack2(x1.z, x1.w));
      bv1 = make_uint4(pack2(x2.x, x2.y), pack2(x2.z, x2.w),
                       pack2(x3.x, x3.y), pack2(x3.z, x3.w));
    } else {
      const u16* pb = first ? (bw0_h + kg) : (bw1_h + (kg - klen0));
      bv0 = *(const uint4*)pb;
      bv1 = *(const uint4*)(pb + 8);
    }
    __syncthreads();  // previous iteration's LDS readers done
    *(uint4*)&As[r][q * 16]     = av0;
    *(uint4*)&As[r][q * 16 + 8] = av1;
    *(uint4*)&Bs[r][q * 16]     = bv0;
    *(uint4*)&Bs[r][q * 16 + 8] = bv1;
    __syncthreads();
#pragma unroll
    for (int ks = 0; ks < 2; ++ks) {
      const int kb = ks * 32 + quad * 8;
      short8 a0 = *(const short8*)&As[wm + l16][kb];
      short8 a1 = *(const short8*)&As[wm + 16 + l16][kb];
      short8 b0 = *(const short8*)&Bs[wn + l16][kb];
      short8 b1 = *(const short8*)&Bs[wn + 16 + l16][kb];
      acc00 = __builtin_amdgcn_mfma_f32_16x16x32_bf16(a0, b0, acc00, 0, 0, 0);
      acc01 = __builtin_amdgcn_mfma_f32_16x16x32_bf16(a0, b1, acc01, 0, 0, 0);
      acc10 = __builtin_amdgcn_mfma_f32_16x16x32_bf16(a1, b0, acc10, 0, 0, 0);
      acc11 = __builtin_amdgcn_mfma_f32_16x16x32_bf16(a1, b1, acc11, 0, 0, 0);
    }
  }

  // spill gates to LDS (C/D layout: col = lane&15, row = quad*4 + reg)
#pragma unroll
  for (int rr = 0; rr < 4; ++rr) {
    Gs[wm + quad * 4 + rr][wn + l16]           = acc00[rr];
    Gs[wm + quad * 4 + rr][wn + 16 + l16]      = acc01[rr];
    Gs[wm + 16 + quad * 4 + rr][wn + l16]      = acc10[rr];
    Gs[wm + 16 + quad * 4 + rr][wn + 16 + l16] = acc11[rr];
  }
  __syncthreads();

  // fused LSTM cell: 64 batches x 16 hidden units; local col 4u+g = gate g of unit ub+u
#pragma unroll
  for (int it = 0; it < 4; ++it) {
    const int p = tid + it * 256;
    const int bl = p >> 4;
    const int u = p & 15;
    const int J = ub + u;
    const int bg = m0 + bl;
    const float4v g = *(const float4v*)&Gs[bl][u * 4];
    float pi = g[0] + biasO[J];
    float pf = g[1] + biasO[H_ + J];
    float pg = g[2] + biasO[2 * H_ + J];
    float po = g[3] + biasO[3 * H_ + J];
    if (inp != nullptr) {
      const float iv = inp[bg];
      pi += iv * wcolO[J];
      pf += iv * wcolO[H_ + J];
      pg += iv * wcolO[2 * H_ + J];
      po += iv * wcolO[3 * H_ + J];
    }
    const size_t idx = (size_t)bg * H_ + J;
    const float c = c_state[idx];
    const float cn = sigm(pf) * c + sigm(pi) * tanh_(pg);
    c_state[idx] = cn;
    h_out[idx] = f2bf(sigm(po) * tanh_(cn));
  }
}

// pred[b] = fc_W . h1[b] + fc_b ; fp32 out + fp32 feedback
__global__ __launch_bounds__(256) void fc_kernel(
    const u16* __restrict__ h1, const float* __restrict__ fcW,
    const float* __restrict__ fcb, float* __restrict__ out,
    float* __restrict__ inp, int t)
{
  const int b = blockIdx.x;
  const int tid = threadIdx.x;
  const u16* hr = h1 + (size_t)b * H_ + tid * 4;
  const float* wr = fcW + tid * 4;
  float s = 0.f;
#pragma unroll
  for (int j = 0; j < 4; ++j) s += bf2f(hr[j]) * wr[j];
#pragma unroll
  for (int off = 32; off > 0; off >>= 1) s += __shfl_down(s, off, 64);
  __shared__ float red[4];
  if ((tid & 63) == 0) red[tid >> 6] = s;
  __syncthreads();
  if (tid == 0) {
    const float p = red[0] + red[1] + red[2] + red[3] + fcb[0];
    out[(size_t)b * TOUT + t] = p;
    inp[b] = p;
  }
}

extern "C" void kernel_launch(void* const* d_in, const int* in_sizes, int n_in,
                              void* d_out, int out_size, void* d_ws, size_t ws_size,
                              hipStream_t stream)
{
  const float* X     = (const float*)d_in[0];
  const float* eWih0 = (const float*)d_in[1];
  const float* eWhh0 = (const float*)d_in[2];
  const float* eb0   = (const float*)d_in[3];
  const float* eWih1 = (const float*)d_in[4];
  const float* eWhh1 = (const float*)d_in[5];
  const float* eb1   = (const float*)d_in[6];
  const float* dWih0 = (const float*)d_in[7];
  const float* dWhh0 = (const float*)d_in[8];
  const float* db0   = (const float*)d_in[9];
  const float* dWih1 = (const float*)d_in[10];
  const float* dWhh1 = (const float*)d_in[11];
  const float* db1   = (const float*)d_in[12];
  const float* fcW   = (const float*)d_in[13];
  const float* fcb   = (const float*)d_in[14];
  float* out = (float*)d_out;

  char* ws = (char*)d_ws;
  size_t off = 0;
  auto alloc = [&](size_t bytes) -> void* {
    void* p = ws + off;
    off += (bytes + 255) & ~(size_t)255;
    return p;
  };
  // state block first (zeroed every call) so the fallback fits a small ws
  u16* H0A = (u16*)alloc((size_t)B_ * H_ * 2);
  u16* H0B = (u16*)alloc((size_t)B_ * H_ * 2);
  u16* H1A = (u16*)alloc((size_t)B_ * H_ * 2);
  u16* H1B = (u16*)alloc((size_t)B_ * H_ * 2);
  float* C0  = (float*)alloc((size_t)B_ * H_ * 4);
  float* C1  = (float*)alloc((size_t)B_ * H_ * 4);
  float* INP = (float*)alloc(B_ * 4);
  const size_t zbytes = off;
  // X as bf16 (always)
  u16* XB = (u16*)alloc((size_t)B_ * S_ * D_ * 2);
  const size_t need_min = off;
  // bf16 weight copies (fast path only), original flat layouts
  u16* WB_eWih0 = (u16*)alloc((size_t)G4 * D_ * 2);
  u16* WB_eWhh0 = (u16*)alloc((size_t)G4 * H_ * 2);
  u16* WB_eWih1 = (u16*)alloc((size_t)G4 * H_ * 2);
  u16* WB_eWhh1 = (u16*)alloc((size_t)G4 * H_ * 2);
  u16* WB_dWhh0 = (u16*)alloc((size_t)G4 * H_ * 2);
  u16* WB_dWih1 = (u16*)alloc((size_t)G4 * H_ * 2);
  u16* WB_dWhh1 = (u16*)alloc((size_t)G4 * H_ * 2);
  const size_t need_full = off;
  const bool fast = (ws_size >= need_full);
  (void)need_min;

  zero_kernel<<<dim3(256), dim3(256), 0, stream>>>((uint4*)ws, (int)(zbytes / 16));
  cvt_kernel<<<dim3(1024), dim3(256), 0, stream>>>(X, XB, B_ * S_ * D_);
  if (fast) {
    cvt_kernel<<<dim3(256), dim3(256), 0, stream>>>(eWih0, WB_eWih0, G4 * D_);
    cvt_kernel<<<dim3(1024), dim3(256), 0, stream>>>(eWhh0, WB_eWhh0, G4 * H_);
    cvt_kernel<<<dim3(1024), dim3(256), 0, stream>>>(eWih1, WB_eWih1, G4 * H_);
    cvt_kernel<<<dim3(1024), dim3(256), 0, stream>>>(eWhh1, WB_eWhh1, G4 * H_);
    cvt_kernel<<<dim3(1024), dim3(256), 0, stream>>>(dWhh0, WB_dWhh0, G4 * H_);
    cvt_kernel<<<dim3(1024), dim3(256), 0, stream>>>(dWih1, WB_dWih1, G4 * H_);
    cvt_kernel<<<dim3(1024), dim3(256), 0, stream>>>(dWhh1, WB_dWhh1, G4 * H_);
  }

  dim3 gg(64, 4), gb(256);
  auto step = [&](const u16* A0, int lda0, const u16* A1, int lda1, int klen0,
                  const void* W0b, const void* W0f, int ldw0,
                  const void* W1b, const void* W1f, int ldw1, int Ktot,
                  const float* bias, const float* wcol, const float* inp,
                  float* c, u16* h) {
    if (fast)
      lstm_step_kernel<false><<<gg, gb, 0, stream>>>(
          A0, lda0, A1, lda1, klen0, W0b, ldw0, W1b, ldw1, Ktot, bias, wcol, inp, c, h);
    else
      lstm_step_kernel<true><<<gg, gb, 0, stream>>>(
          A0, lda0, A1, lda1, klen0, W0f, ldw0, W1f, ldw1, Ktot, bias, wcol, inp, c, h);
  };

  // encoder: h ping-pong (read old parity, write new) avoids cross-block races
  for (int t = 0; t < S_; ++t) {
    u16* h0i = (t & 1) ? H0B : H0A; u16* h0o = (t & 1) ? H0A : H0B;
    u16* h1i = (t & 1) ? H1B : H1A; u16* h1o = (t & 1) ? H1A : H1B;
    step(XB + t * D_, S_ * D_, h0i, H_, D_,
         WB_eWih0, eWih0, D_, WB_eWhh0, eWhh0, H_, 1088,
         eb0, nullptr, nullptr, C0, h0o);
    step(h0o, H_, h1i, H_, H_,
         WB_eWih1, eWih1, H_, WB_eWhh1, eWhh1, H_, 2048,
         eb1, nullptr, nullptr, C1, h1o);
  }
  // decoder: states continue (enc t=255 wrote the A buffers)
  for (int t = 0; t < TOUT; ++t) {
    u16* h0i = (t & 1) ? H0B : H0A; u16* h0o = (t & 1) ? H0A : H0B;
    u16* h1i = (t & 1) ? H1B : H1A; u16* h1o = (t & 1) ? H1A : H1B;
    step(h0i, H_, h0i, H_, H_,
         WB_dWhh0, dWhh0, H_, WB_dWhh0, dWhh0, H_, 1024,
         db0, dWih0, INP, C0, h0o);
    step(h0o, H_, h1i, H_, H_,
         WB_dWih1, dWih1, H_, WB_dWhh1, dWhh1, H_, 2048,
         db1, nullptr, nullptr, C1, h1o);
    fc_kernel<<<dim3(B_), dim3(256), 0, stream>>>(h1o, fcW, fcb, out, INP, t);
  }
}

// Round 3
// 7262.966 us; speedup vs baseline: 1.6389x; 1.6389x over previous
//
#include <hip/hip_runtime.h>

#define B_ 256
#define S_ 256
#define D_ 64
#define H_ 1024
#define G4 4096
#define TOUT 32

typedef unsigned short u16;
typedef __attribute__((ext_vector_type(8))) short short8;
typedef __attribute__((ext_vector_type(4))) float float4v;

__device__ __forceinline__ float bf2f(u16 b) {
  return __uint_as_float(((unsigned int)b) << 16);
}
__device__ __forceinline__ u16 f2bf(float f) {
  unsigned int u = __float_as_uint(f);
  unsigned int r = (u + 0x7fffu + ((u >> 16) & 1u)) >> 16;
  return (u16)r;
}
__device__ __forceinline__ unsigned pack2(float a, float b) {
  return (unsigned)f2bf(a) | ((unsigned)f2bf(b) << 16);
}
__device__ __forceinline__ float sigm(float x) {
  return 1.f / (1.f + __expf(-x));
}
__device__ __forceinline__ float tanh_(float x) {
  float xc = fminf(fmaxf(x, -15.f), 15.f);
  float e = __expf(2.f * xc);
  return (e - 1.f) / (e + 1.f);
}

__global__ __launch_bounds__(256) void cvt_kernel(const float* __restrict__ src,
                                                  u16* __restrict__ dst, int n) {
  for (int i = blockIdx.x * blockDim.x + threadIdx.x; i < n;
       i += gridDim.x * blockDim.x)
    dst[i] = f2bf(src[i]);
}

__global__ __launch_bounds__(256) void zero_kernel(uint4* __restrict__ p, int n16) {
  for (int i = blockIdx.x * blockDim.x + threadIdx.x; i < n16;
       i += gridDim.x * blockDim.x)
    p[i] = make_uint4(0u, 0u, 0u, 0u);
}

struct LayerDesc {
  const u16* A0; int lda0;
  const u16* A1; int lda1; int klen0;
  const void* W0; int ldw0;
  const void* W1; int ldw1; int Ktot;
  const float* bias;   // fp32 [4096] original gate-blocked
  const float* wcol;   // fp32 [4096] dec input column, or null
  const float* inp;    // fp32 [B] scalar input, or null
  float* c;
  u16* h;
  int active;
};

// Paired LSTM step: blockIdx.y<4 -> dA (layer0 @ t), >=4 -> dB (layer1 @ t-1).
// Each 64x64 tile: gates = [A0|A1] @ [W0|W1]^T + bias (+inp*wcol), fused cell.
// K-loop software-pipelined: chunk kc+1 loads issue before MFMA(kc).
template <bool WF32>
__global__ __launch_bounds__(256) void lstm_step_kernel(LayerDesc dA, LayerDesc dB)
{
  const bool second = (blockIdx.y >= 4);
  const LayerDesc d = second ? dB : dA;
  if (!d.active) return;

  __shared__ u16 As[64][72];   // +8 pad: only free 2-way conflicts (m136)
  __shared__ u16 Bs[64][72];
  __shared__ float Gs[64][68];

  const int tid = threadIdx.x;
  const int m0 = (second ? (blockIdx.y - 4) : blockIdx.y) * 64;
  const int n0 = blockIdx.x * 64;
  const int ub = n0 >> 2;        // first hidden unit of this block
  const int r = tid >> 2;        // staging row 0..63
  const int q = tid & 3;         // staging 16-col group
  const int lane = tid & 63;
  const int wv = tid >> 6;
  const int wm = (wv >> 1) * 32;
  const int wn = (wv & 1) * 32;
  const int l16 = lane & 15;
  const int quad = lane >> 4;

  const int klen0 = d.klen0;
  const u16* aw0 = d.A0 + (size_t)(m0 + r) * d.lda0;
  const u16* aw1 = d.A1 + (size_t)(m0 + r) * d.lda1;
  const int orow = (r & 3) * H_ + ub + (r >> 2);  // gate-col n0+r -> original W row
  const u16* bw0_h = (const u16*)d.W0 + (size_t)orow * d.ldw0;
  const u16* bw1_h = (const u16*)d.W1 + (size_t)orow * d.ldw1;
  const float* bw0_f = (const float*)d.W0 + (size_t)orow * d.ldw0;
  const float* bw1_f = (const float*)d.W1 + (size_t)orow * d.ldw1;

  uint4 av0, av1, bv0, bv1;
  float4 bf0, bf1, bf2, bf3;

  auto load_chunk = [&](int kc) {
    const int kg = kc * 64 + q * 16;
    const bool first = kg < klen0;
    const u16* pa = first ? (aw0 + kg) : (aw1 + (kg - klen0));
    av0 = *(const uint4*)pa;
    av1 = *(const uint4*)(pa + 8);
    if constexpr (WF32) {
      const float* pb = first ? (bw0_f + kg) : (bw1_f + (kg - klen0));
      bf0 = *(const float4*)pb;
      bf1 = *(const float4*)(pb + 4);
      bf2 = *(const float4*)(pb + 8);
      bf3 = *(const float4*)(pb + 12);
    } else {
      const u16* pb = first ? (bw0_h + kg) : (bw1_h + (kg - klen0));
      bv0 = *(const uint4*)pb;
      bv1 = *(const uint4*)(pb + 8);
    }
  };

  float4v acc00 = {}, acc01 = {}, acc10 = {}, acc11 = {};
  const int nch = d.Ktot >> 6;
  load_chunk(0);
  for (int kc = 0; kc < nch; ++kc) {
    if constexpr (WF32) {
      bv0 = make_uint4(pack2(bf0.x, bf0.y), pack2(bf0.z, bf0.w),
                       pack2(bf1.x, bf1.y), pack2(bf1.z, bf1.w));
      bv1 = make_uint4(pack2(bf2.x, bf2.y), pack2(bf2.z, bf2.w),
                       pack2(bf3.x, bf3.y), pack2(bf3.z, bf3.w));
    }
    __syncthreads();  // previous chunk's LDS readers done
    *(uint4*)&As[r][q * 16]     = av0;
    *(uint4*)&As[r][q * 16 + 8] = av1;
    *(uint4*)&Bs[r][q * 16]     = bv0;
    *(uint4*)&Bs[r][q * 16 + 8] = bv1;
    __syncthreads();
    if (kc + 1 < nch) load_chunk(kc + 1);  // in flight across MFMA below
#pragma unroll
    for (int ks = 0; ks < 2; ++ks) {
      const int kb = ks * 32 + quad * 8;
      short8 a0 = *(const short8*)&As[wm + l16][kb];
      short8 a1 = *(const short8*)&As[wm + 16 + l16][kb];
      short8 b0 = *(const short8*)&Bs[wn + l16][kb];
      short8 b1 = *(const short8*)&Bs[wn + 16 + l16][kb];
      acc00 = __builtin_amdgcn_mfma_f32_16x16x32_bf16(a0, b0, acc00, 0, 0, 0);
      acc01 = __builtin_amdgcn_mfma_f32_16x16x32_bf16(a0, b1, acc01, 0, 0, 0);
      acc10 = __builtin_amdgcn_mfma_f32_16x16x32_bf16(a1, b0, acc10, 0, 0, 0);
      acc11 = __builtin_amdgcn_mfma_f32_16x16x32_bf16(a1, b1, acc11, 0, 0, 0);
    }
  }

  // spill gates to LDS (C/D layout: col = lane&15, row = quad*4 + reg)
#pragma unroll
  for (int rr = 0; rr < 4; ++rr) {
    Gs[wm + quad * 4 + rr][wn + l16]           = acc00[rr];
    Gs[wm + quad * 4 + rr][wn + 16 + l16]      = acc01[rr];
    Gs[wm + 16 + quad * 4 + rr][wn + l16]      = acc10[rr];
    Gs[wm + 16 + quad * 4 + rr][wn + 16 + l16] = acc11[rr];
  }
  __syncthreads();

  // fused LSTM cell: 64 batches x 16 units; local col 4u+g = gate g of unit ub+u
#pragma unroll
  for (int it = 0; it < 4; ++it) {
    const int p = tid + it * 256;
    const int bl = p >> 4;
    const int u = p & 15;
    const int J = ub + u;
    const int bg = m0 + bl;
    const float4v g = *(const float4v*)&Gs[bl][u * 4];
    float pi = g[0] + d.bias[J];
    float pf = g[1] + d.bias[H_ + J];
    float pg = g[2] + d.bias[2 * H_ + J];
    float po = g[3] + d.bias[3 * H_ + J];
    if (d.inp != nullptr) {
      const float iv = d.inp[bg];
      pi += iv * d.wcol[J];
      pf += iv * d.wcol[H_ + J];
      pg += iv * d.wcol[2 * H_ + J];
      po += iv * d.wcol[3 * H_ + J];
    }
    const size_t idx = (size_t)bg * H_ + J;
    const float c = d.c[idx];
    const float cn = sigm(pf) * c + sigm(pi) * tanh_(pg);
    d.c[idx] = cn;
    d.h[idx] = f2bf(sigm(po) * tanh_(cn));
  }
}

// pred[b] = fc_W . h1[b] + fc_b ; fp32 out + fp32 feedback
__global__ __launch_bounds__(256) void fc_kernel(
    const u16* __restrict__ h1, const float* __restrict__ fcW,
    const float* __restrict__ fcb, float* __restrict__ out,
    float* __restrict__ inp, int t)
{
  const int b = blockIdx.x;
  const int tid = threadIdx.x;
  const u16* hr = h1 + (size_t)b * H_ + tid * 4;
  const float* wr = fcW + tid * 4;
  float s = 0.f;
#pragma unroll
  for (int j = 0; j < 4; ++j) s += bf2f(hr[j]) * wr[j];
#pragma unroll
  for (int off = 32; off > 0; off >>= 1) s += __shfl_down(s, off, 64);
  __shared__ float red[4];
  if ((tid & 63) == 0) red[tid >> 6] = s;
  __syncthreads();
  if (tid == 0) {
    const float p = red[0] + red[1] + red[2] + red[3] + fcb[0];
    out[(size_t)b * TOUT + t] = p;
    inp[b] = p;
  }
}

extern "C" void kernel_launch(void* const* d_in, const int* in_sizes, int n_in,
                              void* d_out, int out_size, void* d_ws, size_t ws_size,
                              hipStream_t stream)
{
  const float* X     = (const float*)d_in[0];
  const float* eWih0 = (const float*)d_in[1];
  const float* eWhh0 = (const float*)d_in[2];
  const float* eb0   = (const float*)d_in[3];
  const float* eWih1 = (const float*)d_in[4];
  const float* eWhh1 = (const float*)d_in[5];
  const float* eb1   = (const float*)d_in[6];
  const float* dWih0 = (const float*)d_in[7];
  const float* dWhh0 = (const float*)d_in[8];
  const float* db0   = (const float*)d_in[9];
  const float* dWih1 = (const float*)d_in[10];
  const float* dWhh1 = (const float*)d_in[11];
  const float* db1   = (const float*)d_in[12];
  const float* fcW   = (const float*)d_in[13];
  const float* fcb   = (const float*)d_in[14];
  float* out = (float*)d_out;

  char* ws = (char*)d_ws;
  size_t off = 0;
  auto alloc = [&](size_t bytes) -> void* {
    void* p = ws + off;
    off += (bytes + 255) & ~(size_t)255;
    return p;
  };
  // state block first (zeroed every call)
  u16* h0buf[2], *h1buf[2];
  h0buf[0] = (u16*)alloc((size_t)B_ * H_ * 2);
  h0buf[1] = (u16*)alloc((size_t)B_ * H_ * 2);
  h1buf[0] = (u16*)alloc((size_t)B_ * H_ * 2);
  h1buf[1] = (u16*)alloc((size_t)B_ * H_ * 2);
  float* C0  = (float*)alloc((size_t)B_ * H_ * 4);
  float* C1  = (float*)alloc((size_t)B_ * H_ * 4);
  float* INP = (float*)alloc(B_ * 4);
  const size_t zbytes = off;
  u16* XB = (u16*)alloc((size_t)B_ * S_ * D_ * 2);
  // bf16 weight copies (fast path), original flat layouts
  u16* WB_eWih0 = (u16*)alloc((size_t)G4 * D_ * 2);
  u16* WB_eWhh0 = (u16*)alloc((size_t)G4 * H_ * 2);
  u16* WB_eWih1 = (u16*)alloc((size_t)G4 * H_ * 2);
  u16* WB_eWhh1 = (u16*)alloc((size_t)G4 * H_ * 2);
  u16* WB_dWhh0 = (u16*)alloc((size_t)G4 * H_ * 2);
  u16* WB_dWih1 = (u16*)alloc((size_t)G4 * H_ * 2);
  u16* WB_dWhh1 = (u16*)alloc((size_t)G4 * H_ * 2);
  const size_t need_full = off;
  const bool fast = (ws_size >= need_full);

  zero_kernel<<<dim3(256), dim3(256), 0, stream>>>((uint4*)ws, (int)(zbytes / 16));
  cvt_kernel<<<dim3(1024), dim3(256), 0, stream>>>(X, XB, B_ * S_ * D_);
  if (fast) {
    cvt_kernel<<<dim3(256), dim3(256), 0, stream>>>(eWih0, WB_eWih0, G4 * D_);
    cvt_kernel<<<dim3(1024), dim3(256), 0, stream>>>(eWhh0, WB_eWhh0, G4 * H_);
    cvt_kernel<<<dim3(1024), dim3(256), 0, stream>>>(eWih1, WB_eWih1, G4 * H_);
    cvt_kernel<<<dim3(1024), dim3(256), 0, stream>>>(eWhh1, WB_eWhh1, G4 * H_);
    cvt_kernel<<<dim3(1024), dim3(256), 0, stream>>>(dWhh0, WB_dWhh0, G4 * H_);
    cvt_kernel<<<dim3(1024), dim3(256), 0, stream>>>(dWih1, WB_dWih1, G4 * H_);
    cvt_kernel<<<dim3(1024), dim3(256), 0, stream>>>(dWhh1, WB_dWhh1, G4 * H_);
  }

  auto mk = [&](const u16* A0, int lda0, const u16* A1, int lda1, int klen0,
                const void* W0b, const void* W0f, int ldw0,
                const void* W1b, const void* W1f, int ldw1, int Ktot,
                const float* bias, const float* wcol, const float* inp,
                float* c, u16* h) {
    LayerDesc d;
    d.A0 = A0; d.lda0 = lda0; d.A1 = A1; d.lda1 = lda1; d.klen0 = klen0;
    d.W0 = fast ? W0b : W0f; d.ldw0 = ldw0;
    d.W1 = fast ? W1b : W1f; d.ldw1 = ldw1; d.Ktot = Ktot;
    d.bias = bias; d.wcol = wcol; d.inp = inp; d.c = c; d.h = h;
    d.active = 1;
    return d;
  };
  LayerDesc off_d = {};
  off_d.active = 0;

  auto launch = [&](dim3 grid, const LayerDesc& a, const LayerDesc& b) {
    if (fast)
      lstm_step_kernel<false><<<grid, dim3(256), 0, stream>>>(a, b);
    else
      lstm_step_kernel<true><<<grid, dim3(256), 0, stream>>>(a, b);
  };

  // encoder, layer-pipelined: tick u runs L0(t=u) and L1(t=u-1) concurrently.
  // h ping-pong: L(t) reads hbuf[t&1], writes hbuf[(t+1)&1].
  for (int u = 0; u <= S_; ++u) {
    LayerDesc d0 = off_d, d1 = off_d;
    if (u < S_) {
      const int t = u;
      d0 = mk(XB + t * D_, S_ * D_, h0buf[t & 1], H_, D_,
              WB_eWih0, eWih0, D_, WB_eWhh0, eWhh0, H_, 1088,
              eb0, nullptr, nullptr, C0, h0buf[(t + 1) & 1]);
    }
    if (u >= 1) {
      const int t = u - 1;
      d1 = mk(h0buf[(t + 1) & 1], H_, h1buf[t & 1], H_, H_,
              WB_eWih1, eWih1, H_, WB_eWhh1, eWhh1, H_, 2048,
              eb1, nullptr, nullptr, C1, h1buf[(t + 1) & 1]);
    }
    launch(dim3(64, 8), d0, d1);
  }

  // decoder: strictly sequential (pred feedback), single-layer launches
  for (int t = 0; t < TOUT; ++t) {
    u16* h0i = h0buf[t & 1]; u16* h0o = h0buf[(t + 1) & 1];
    u16* h1i = h1buf[t & 1]; u16* h1o = h1buf[(t + 1) & 1];
    LayerDesc dl0 = mk(h0i, H_, h0i, H_, 1024,
                       WB_dWhh0, dWhh0, H_, WB_dWhh0, dWhh0, H_, 1024,
                       db0, dWih0, INP, C0, h0o);
    launch(dim3(64, 4), dl0, off_d);
    LayerDesc dl1 = mk(h0o, H_, h1i, H_, H_,
                       WB_dWih1, dWih1, H_, WB_dWhh1, dWhh1, H_, 2048,
                       db1, nullptr, nullptr, C1, h1o);
    launch(dim3(64, 4), dl1, off_d);
    fc_kernel<<<dim3(B_), dim3(256), 0, stream>>>(h1o, fcW, fcb, out, INP, t);
  }
}